// Round 6
// baseline (340.722 us; speedup 1.0000x reference)
//
#include <hip/hip_runtime.h>

// VQ-VAE vector quantizer, fp32, MI355X — round 6: barrier-free main loop,
// codebook read direct from L1/L2 (no LDS staging; traffic is identical —
// broadcast loads, 4 addrs/wave — but 17 KB LDS + 32 barriers disappear).
// N=131072 rows, D=64, K=1024. d_out = quantized[8388608] + loss[1] + indices[131072].
// Block = 256 threads (16x16), 64 rows x 1024 codes; thread computes 4x4 tile.
// Numerics verbatim round 5 (absmax 0.0): acc over d ascending sequential-FMA,
// dist = (sx+se[j]) - 2.0f*acc, ascending strict <, tie -> smaller index.

constexpr int Dm = 64;
constexpr int Kn = 1024;
constexpr long NR = 131072;
constexpr long QE = NR * (long)Dm;   // 8388608
constexpr int RB = 64;               // rows per block
constexpr int NBLK = (int)(NR / RB); // 2048
constexpr int CH = 64;               // codes per accumulation chunk
constexpr int NCH = Kn / CH;         // 16
constexpr int SP4 = 17;              // padded row stride in float4s (68 floats)

__global__ __launch_bounds__(256) void vq_norms(const float* __restrict__ cb,
                                                float* __restrict__ se)
{
    int j = blockIdx.x * 256 + threadIdx.x;   // 4 blocks x 256 = 1024
    const float* e = cb + (size_t)j * Dm;
    float s = 0.f;
    #pragma unroll
    for (int d = 0; d < Dm; ++d) s = fmaf(e[d], e[d], s);  // same bits as r1-r5
    se[j] = s;
}

__global__ __launch_bounds__(256, 5) void vq_main(const float* __restrict__ inp,
                                                  const float* __restrict__ cb,
                                                  const float* __restrict__ seg,
                                                  float* __restrict__ out,
                                                  double* __restrict__ part)
{
    __shared__ float4 xs[RB * SP4];   // 17408 B row tile
    __shared__ float  sxs[RB];
    __shared__ float  bd[RB * 17];    // padded: conflict-light combine reads
    __shared__ int    bi[RB * 17];
    __shared__ int    comb[RB];
    __shared__ double red[256];       // total ~28.7 KB -> 5 blocks/CU

    const int tid = threadIdx.x;
    const int tr = tid & 15;          // row-group id   (rows tr + 16*rr)
    const int tc = tid >> 4;          // code-group id  (codes tc + 16*cc)

    // stage row tile (coalesced)
    {
        const float4* src = reinterpret_cast<const float4*>(
            inp + (size_t)blockIdx.x * RB * Dm);
        #pragma unroll
        for (int r = 0; r < 4; ++r) {
            int g = r * 256 + tid;                      // 0..1023 float4s
            xs[(g >> 4) * SP4 + (g & 15)] = src[g];
        }
    }
    __syncthreads();

    // per-row ||x||^2, sequential-FMA over d (reference op order, bits as r1-r5)
    if (tid < RB) {
        const float* xr = reinterpret_cast<const float*>(&xs[tid * SP4]);
        float s = 0.f;
        #pragma unroll
        for (int d = 0; d < Dm; ++d) s = fmaf(xr[d], xr[d], s);
        sxs[tid] = s;
    }
    __syncthreads();

    float sxr[4];
    #pragma unroll
    for (int rr = 0; rr < 4; ++rr) sxr[rr] = sxs[tr + 16 * rr];

    float best[4]; int bidx[4];
    #pragma unroll
    for (int rr = 0; rr < 4; ++rr) { best[rr] = __builtin_inff(); bidx[rr] = 0; }

    // barrier-free main loop: codebook fragments direct from global (L1/L2-hot,
    // 4 distinct addresses per wave-instruction = pure broadcast)
    for (int ch = 0; ch < NCH; ++ch) {
        const int cbase = ch * CH;
        const float4* ec0 = reinterpret_cast<const float4*>(
            cb + (size_t)(cbase + tc) * Dm);            // code tc + 16*cc rows

        float acc[4][4];
        #pragma unroll
        for (int rr = 0; rr < 4; ++rr)
            #pragma unroll
            for (int cc = 0; cc < 4; ++cc) acc[rr][cc] = 0.f;

        #pragma unroll 4
        for (int db = 0; db < 16; ++db) {               // d-block of 4, ascending
            float4 xf[4], ef[4];
            #pragma unroll
            for (int cc = 0; cc < 4; ++cc) ef[cc] = ec0[cc * (16 * Dm / 4) + db];
            #pragma unroll
            for (int rr = 0; rr < 4; ++rr) xf[rr] = xs[(tr + 16 * rr) * SP4 + db];
            #pragma unroll
            for (int rr = 0; rr < 4; ++rr)
                #pragma unroll
                for (int cc = 0; cc < 4; ++cc) {
                    float a = acc[rr][cc];
                    a = fmaf(xf[rr].x, ef[cc].x, a);    // d = 4*db+0 .. +3 in order
                    a = fmaf(xf[rr].y, ef[cc].y, a);
                    a = fmaf(xf[rr].z, ef[cc].z, a);
                    a = fmaf(xf[rr].w, ef[cc].w, a);
                    acc[rr][cc] = a;
                }
        }

        #pragma unroll
        for (int cc = 0; cc < 4; ++cc) {                // codes ascending per thread
            const int code = cbase + tc + 16 * cc;
            const float sec = seg[code];                // L1-hot 4 KB
            #pragma unroll
            for (int rr = 0; rr < 4; ++rr) {
                float dist = (sxr[rr] + sec) - 2.0f * acc[rr][cc];  // r1-r5 formula
                if (dist < best[rr]) { best[rr] = dist; bidx[rr] = code; }
            }
        }
    }

    #pragma unroll
    for (int rr = 0; rr < 4; ++rr) {
        int row = tr + 16 * rr;
        bd[row * 17 + tc] = best[rr];
        bi[row * 17 + tc] = bidx[rr];
    }
    __syncthreads();

    // combine 16 code-subsets per row: min dist, tie -> smaller index
    if (tid < RB) {
        float b = bd[tid * 17]; int ii = bi[tid * 17];
        #pragma unroll
        for (int q = 1; q < 16; ++q) {
            float d = bd[tid * 17 + q]; int iq = bi[tid * 17 + q];
            if (d < b || (d == b && iq < ii)) { b = d; ii = iq; }
        }
        comb[tid] = ii;
        out[QE + 1 + (long)blockIdx.x * RB + tid] = (float)ii;
    }
    __syncthreads();

    // quantized write (verbatim r4/r5 epilogue): thread -> (row tid>>2, quarter tid&3)
    const int r2 = tid >> 2;
    const int dq = (tid & 3) * 16;
    const long grow = (long)blockIdx.x * RB + r2;
    const float* xr2 = inp + grow * (long)Dm + dq;
    const float* q2  = cb + (size_t)comb[r2] * Dm + dq;
    float* outq = out + grow * (long)Dm + dq;
    double s = 0.0;
    #pragma unroll
    for (int d0 = 0; d0 < 16; d0 += 4) {
        float4 xv = *reinterpret_cast<const float4*>(xr2 + d0);
        float4 qv = *reinterpret_cast<const float4*>(q2 + d0);
        float4 ov;
        float m0 = qv.x - xv.x; ov.x = xv.x + m0;   // replicate x + (q - x)
        float m1 = qv.y - xv.y; ov.y = xv.y + m1;
        float m2 = qv.z - xv.z; ov.z = xv.z + m2;
        float m3 = qv.w - xv.w; ov.w = xv.w + m3;
        s += (double)m0 * m0 + (double)m1 * m1 + (double)m2 * m2 + (double)m3 * m3;
        *reinterpret_cast<float4*>(outq + d0) = ov;
    }

    red[tid] = s;
    __syncthreads();
    for (int k = 128; k > 0; k >>= 1) {
        if (tid < k) red[tid] += red[tid + k];
        __syncthreads();
    }
    if (tid == 0) part[blockIdx.x] = red[0];
}

__global__ __launch_bounds__(256) void vq_fin(const double* __restrict__ part,
                                              float* __restrict__ out)
{
    __shared__ double red[256];
    const int tid = threadIdx.x;
    double s = 0.0;
    #pragma unroll
    for (int k = 0; k < 8; ++k) s += part[tid + 256 * k];   // fixed order
    red[tid] = s;
    __syncthreads();
    for (int k = 128; k > 0; k >>= 1) {
        if (tid < k) red[tid] += red[tid + k];
        __syncthreads();
    }
    if (tid == 0) {
        float m = (float)(red[0] / (double)QE);   // mean((q-x)^2)
        out[QE] = m + 0.25f * m;                  // q_loss + 0.25 * e_loss
    }
}

extern "C" void kernel_launch(void* const* d_in, const int* in_sizes, int n_in,
                              void* d_out, int out_size, void* d_ws, size_t ws_size,
                              hipStream_t stream)
{
    const float* inp = (const float*)d_in[0];
    const float* cb  = (const float*)d_in[1];
    float* out = (float*)d_out;
    float* se    = (float*)d_ws;                    // 4 KB
    double* part = (double*)((char*)d_ws + 4096);   // 16 KB

    vq_norms<<<4, 256, 0, stream>>>(cb, se);
    vq_main<<<NBLK, 256, 0, stream>>>(inp, cb, se, out, part);
    vq_fin<<<1, 256, 0, stream>>>(part, out);
}